// Round 11
// baseline (142.419 us; speedup 1.0000x reference)
//
#include <hip/hip_runtime.h>
#include <stdint.h>

#define T_TOK  2048
#define HID    1024
#define INTERN 2048
#define NEXP   8
#define MAXPOS 5248   // max 128-aligned routed rows (41 blocks of 128)

typedef __attribute__((ext_vector_type(8))) short          bf16x8;
typedef __attribute__((ext_vector_type(4))) float          f32x4;
typedef __attribute__((ext_vector_type(8))) unsigned short u16x8;
typedef __attribute__((ext_vector_type(4))) unsigned short u16x4;

__device__ __forceinline__ unsigned short f32_to_bf16(float f) {
  unsigned int u = __float_as_uint(f);
  unsigned int r = (u + 0x7FFFu + ((u >> 16) & 1u)) >> 16;
  return (unsigned short)r;
}

__device__ __forceinline__ float bf16_to_f32(unsigned short h) {
  unsigned int u = ((unsigned int)h) << 16;
  return __uint_as_float(u);
}

__device__ __forceinline__ void gload_lds16(const void* g, void* l) {
  __builtin_amdgcn_global_load_lds(
      (const __attribute__((address_space(1))) unsigned int*)g,
      (__attribute__((address_space(3))) unsigned int*)l, 16, 0, 0);
}

// packed f32->bf16 (RTNE) via v_cvt_pk_bf16_f32: 4 inst per 8 elements
__device__ __forceinline__ u16x8 cvt8(float4 a, float4 b) {
  union { u16x8 s; unsigned int u[4]; } r;
  asm("v_cvt_pk_bf16_f32 %0, %1, %2" : "=v"(r.u[0]) : "v"(a.x), "v"(a.y));
  asm("v_cvt_pk_bf16_f32 %0, %1, %2" : "=v"(r.u[1]) : "v"(a.z), "v"(a.w));
  asm("v_cvt_pk_bf16_f32 %0, %1, %2" : "=v"(r.u[2]) : "v"(b.x), "v"(b.y));
  asm("v_cvt_pk_bf16_f32 %0, %1, %2" : "=v"(r.u[3]) : "v"(b.z), "v"(b.w));
  return r.s;
}

#define WAIT_VM0()    asm volatile("s_waitcnt vmcnt(0)" ::: "memory")
#define WAIT_VM4()    asm volatile("s_waitcnt vmcnt(4)" ::: "memory")
#define WAIT_LGKM0()  asm volatile("s_waitcnt lgkmcnt(0)" ::: "memory")
#define SCHED_FENCE() __builtin_amdgcn_sched_barrier(0)

// ---------------- routing ----------------
__global__ void route_kernel(const int* __restrict__ tki,
                             const float* __restrict__ tkw,
                             int* __restrict__ counts,
                             int* __restrict__ offsets,
                             int* __restrict__ tok_list,
                             float* __restrict__ w_list,
                             int* __restrict__ pos_map,
                             float* __restrict__ wgt_map) {
  __shared__ int scnt[NEXP];
  __shared__ int soff[NEXP];
  int tid = threadIdx.x;
  if (tid < NEXP) scnt[tid] = 0;
  __syncthreads();
  for (int t = tid; t < T_TOK; t += 256) {
    int e0 = tki[2 * t] & 7;
    int e1 = tki[2 * t + 1] & 7;
    float w0 = tkw[2 * t];
    float w1 = tkw[2 * t + 1];
    if (e0 == e1) {
      int p = atomicAdd(&scnt[e0], 1);
      tok_list[e0 * T_TOK + p] = t;
      w_list [e0 * T_TOK + p] = w0 + w1;
      pos_map[2 * t]     = (p << 3) | e0;
      wgt_map[2 * t]     = w0 + w1;
      pos_map[2 * t + 1] = -1;
      wgt_map[2 * t + 1] = 0.0f;
    } else {
      int p = atomicAdd(&scnt[e0], 1);
      tok_list[e0 * T_TOK + p] = t;
      w_list [e0 * T_TOK + p] = w0;
      pos_map[2 * t]     = (p << 3) | e0;
      wgt_map[2 * t]     = w0;
      int q = atomicAdd(&scnt[e1], 1);
      tok_list[e1 * T_TOK + q] = t;
      w_list [e1 * T_TOK + q] = w1;
      pos_map[2 * t + 1] = (q << 3) | e1;
      wgt_map[2 * t + 1] = w1;
    }
  }
  __syncthreads();
  if (tid == 0) {
    int acc = 0;
    for (int e = 0; e < NEXP; ++e) {
      counts[e]  = scnt[e];
      offsets[e] = acc;
      soff[e]    = acc;
      acc += ((scnt[e] + 127) >> 7) << 7;
    }
  }
  __syncthreads();
  for (int i = tid; i < 2 * T_TOK; i += 256) {
    int v = pos_map[i];
    if (v >= 0) pos_map[i] = soff[v & 7] + (v >> 3);
  }
}

// ---------------- fused gather + f32->bf16: hidden -> blocked xg ----------------
__global__ void gather_cvt_x_kernel(const float* __restrict__ hidden,
                                    const int* __restrict__ counts,
                                    const int* __restrict__ offsets,
                                    const int* __restrict__ tok_list,
                                    unsigned short* __restrict__ xg) {
  int p = blockIdx.x * 2 + (threadIdx.x >> 7);   // routed position
  int c = threadIdx.x & 127;                     // 8-elem column group
  int e = 0;
#pragma unroll
  for (int k = 1; k < NEXP; ++k) if (p >= offsets[k]) e = k;
  int r = p - offsets[e];
  float4 a = {0.f, 0.f, 0.f, 0.f}, b = {0.f, 0.f, 0.f, 0.f};
  if (r < counts[e]) {
    int tok = tok_list[e * T_TOK + r];
    const float4* src = (const float4*)(hidden + (size_t)tok * HID + c * 8);
    a = src[0]; b = src[1];
  }
  *((u16x8*)(xg + (size_t)(p >> 7) * 131072 + c * 1024 + (p & 127) * 8)) = cvt8(a, b);
}

// ---------------- GEMM1: h = gelu_tanh(X Wg^T) * (X Wu^T) ----------------
// BK=32. A fragments DIRECT from global (blocked xg, contiguous per 16-lane group),
// double-buffered in named register sets. B: reg-prefetch + cvt_pk + swizzled LDS.
// LDS = 16 KB (B only). No global_load_lds; no hand vmcnt.
#define G1_STEP(CUR, NXT, T, AFC, AFL)                                                             \
  {                                                                                                \
    int kg_ = lane >> 4;                                                                           \
    int rl_ = lane & 15;                                                                           \
    bf16x8 gf[2], uf[2];                                                                           \
    _Pragma("unroll")                                                                              \
    for (int n = 0; n < 2; ++n) {                                                                  \
      int r_ = (wn * 32 + n * 16 + rl_) ^ kg_;                                                     \
      gf[n] = *((const bf16x8*)&Gs[CUR][kg_][r_][0]);                                              \
      uf[n] = *((const bf16x8*)&Us[CUR][kg_][r_][0]);                                              \
    }                                                                                              \
    {  /* prefetch A fragments for tile T+1 (global, L2-hot, per-lane) */                          \
      int tn_ = ((T) + 1 < NT) ? (T) + 1 : 0;                                                      \
      const unsigned short* ap_ = afbase + (size_t)(tn_ * 4 + kg_) * 1024 + rl_ * 8 + wm * 512;    \
      AFL##0 = *((const bf16x8*)(ap_));                                                            \
      AFL##1 = *((const bf16x8*)(ap_ + 128));                                                      \
      AFL##2 = *((const bf16x8*)(ap_ + 256));                                                      \
      AFL##3 = *((const bf16x8*)(ap_ + 384));                                                      \
    }                                                                                              \
    SCHED_FENCE();                                                                                 \
    _Pragma("unroll")                                                                              \
    for (int n = 0; n < 2; ++n) {                                                                  \
      accg[0][n] = __builtin_amdgcn_mfma_f32_16x16x32_bf16(AFC##0, gf[n], accg[0][n], 0, 0, 0);    \
      accu[0][n] = __builtin_amdgcn_mfma_f32_16x16x32_bf16(AFC##0, uf[n], accu[0][n], 0, 0, 0);    \
      accg[1][n] = __builtin_amdgcn_mfma_f32_16x16x32_bf16(AFC##1, gf[n], accg[1][n], 0, 0, 0);    \
      accu[1][n] = __builtin_amdgcn_mfma_f32_16x16x32_bf16(AFC##1, uf[n], accu[1][n], 0, 0, 0);    \
      accg[2][n] = __builtin_amdgcn_mfma_f32_16x16x32_bf16(AFC##2, gf[n], accg[2][n], 0, 0, 0);    \
      accu[2][n] = __builtin_amdgcn_mfma_f32_16x16x32_bf16(AFC##2, uf[n], accu[2][n], 0, 0, 0);    \
      accg[3][n] = __builtin_amdgcn_mfma_f32_16x16x32_bf16(AFC##3, gf[n], accg[3][n], 0, 0, 0);    \
      accu[3][n] = __builtin_amdgcn_mfma_f32_16x16x32_bf16(AFC##3, uf[n], accu[3][n], 0, 0, 0);    \
    }                                                                                              \
    /* stage B(T+1) -> LDS[NXT] */                                                                 \
    *((u16x8*)&Gs[NXT][bq][brw][0]) = cvt8(g0, g1);                                                \
    *((u16x8*)&Us[NXT][bq][brw][0]) = cvt8(u0, u1);                                                \
    SCHED_FENCE();                                                                                 \
    {  /* load B(T+2) f32 regs */                                                                  \
      int kb_ = ((T) + 2 < NT) ? ((T) + 2) * 32 : 0;                                               \
      const float4* gp_ = (const float4*)(gsrc + kb_);                                             \
      const float4* up_ = (const float4*)(usrc + kb_);                                             \
      g0 = gp_[0]; g1 = gp_[1]; u0 = up_[0]; u1 = up_[1];                                          \
    }                                                                                              \
    WAIT_LGKM0(); SCHED_FENCE();                                                                   \
    __builtin_amdgcn_s_barrier(); SCHED_FENCE();                                                   \
  }

__global__ __launch_bounds__(256, 3)
void gemm1_kernel(const unsigned short* __restrict__ xg,
                  const float* __restrict__ gup,
                  const int* __restrict__ counts,
                  const int* __restrict__ offsets,
                  unsigned short* __restrict__ hbuf) {
  int e  = blockIdx.z;
  int Ne = counts[e];
  int m0 = blockIdx.y * 128;
  if (m0 >= Ne) return;
  int n0  = blockIdx.x * 64;
  int off = offsets[e];

  __shared__ __align__(16) unsigned short Gs[2][4][64][8];   // 8 KB
  __shared__ __align__(16) unsigned short Us[2][4][64][8];   // 8 KB

  int tid  = threadIdx.x;
  int lane = tid & 63;
  int wave = tid >> 6;
  int wm = wave >> 1;
  int wn = wave & 1;

  // A direct-load base: blocked xg chunk for rows [m0, m0+128)
  const unsigned short* afbase = xg + (size_t)((off + m0) >> 7) * (HID * 128);

  int brow = tid >> 2;
  int bq   = tid & 3;           // k-group 0..3
  const float* gsrc = gup + (size_t)e * (2 * INTERN) * HID + (size_t)(n0 + brow) * HID + bq * 8;
  const float* usrc = gsrc + (size_t)INTERN * HID;
  int brw = brow ^ bq;          // XOR-swizzled write row

  f32x4 accg[4][2], accu[4][2];
#pragma unroll
  for (int m = 0; m < 4; ++m)
#pragma unroll
    for (int n = 0; n < 2; ++n) {
      accg[m][n] = (f32x4){0.f, 0.f, 0.f, 0.f};
      accu[m][n] = (f32x4){0.f, 0.f, 0.f, 0.f};
    }

  const int NT = HID / 32;   // 32 (even)

  bf16x8 afX0, afX1, afX2, afX3;   // A-frag set X
  bf16x8 afY0, afY1, afY2, afY3;   // A-frag set Y
  float4 g0, g1, u0, u1;           // B f32 in-flight regs

  // ---- prologue: B(0)->LDS0; afX = tile 0; B(1)->regs ----
  {
    const float4* gp = (const float4*)gsrc;
    const float4* up = (const float4*)usrc;
    float4 tg0 = gp[0], tg1 = gp[1], tu0 = up[0], tu1 = up[1];
    *((u16x8*)&Gs[0][bq][brw][0]) = cvt8(tg0, tg1);
    *((u16x8*)&Us[0][bq][brw][0]) = cvt8(tu0, tu1);
    int kg_ = lane >> 4;
    int rl_ = lane & 15;
    const unsigned short* ap = afbase + (size_t)kg_ * 1024 + rl_ * 8 + wm * 512;
    afX0 = *((const bf16x8*)(ap));
    afX1 = *((const bf16x8*)(ap + 128));
    afX2 = *((const bf16x8*)(ap + 256));
    afX3 = *((const bf16x8*)(ap + 384));
    const float4* gp1 = (const float4*)(gsrc + 32);
    const float4* up1 = (const float4*)(usrc + 32);
    g0 = gp1[0]; g1 = gp1[1]; u0 = up1[0]; u1 = up1[1];
    WAIT_LGKM0(); SCHED_FENCE();
    __builtin_amdgcn_s_barrier(); SCHED_FENCE();
  }

  for (int tt = 0; tt < NT; tt += 2) {
    G1_STEP(0, 1, tt,     afX, afY);
    G1_STEP(1, 0, tt + 1, afY, afX);
  }

  int rl = lane & 15;
  int rq = lane >> 4;
  size_t hb_base = (size_t)((off + m0) >> 7) * (INTERN * 128);
#pragma unroll
  for (int m = 0; m < 4; ++m) {
#pragma unroll
    for (int n = 0; n < 2; ++n) {
      int col = n0 + wn * 32 + n * 16 + rl;
      size_t cbase = hb_base + (size_t)(col >> 3) * 1024 + (col & 7);
#pragma unroll
      for (int j = 0; j < 4; ++j) {
        int lr = wm * 64 + m * 16 + rq * 4 + j;
        if (m0 + lr < Ne) {
          float gv = accg[m][n][j];
          float uv = accu[m][n][j];
          float tt2 = gv + 0.044715f * gv * gv * gv;
          float a  = gv / (1.0f + __expf(-1.5957691216f * tt2));  // == gelu_pytorch_tanh
          hbuf[cbase + (size_t)lr * 8] = f32_to_bf16(a * uv);
        }
      }
    }
  }
}

// ---------------- GEMM2: y = h Wd^T (blocked-A, BK=64, late-B + vmcnt(4)) ----------------
__global__ __launch_bounds__(256, 2)
void gemm2_kernel(const unsigned short* __restrict__ hbuf,
                  const float* __restrict__ down,
                  const int* __restrict__ counts,
                  const int* __restrict__ offsets,
                  unsigned short* __restrict__ ybuf) {
  int e  = blockIdx.z;
  int Ne = counts[e];
  int m0 = blockIdx.y * 128;
  if (m0 >= Ne) return;
  int n0  = blockIdx.x * 64;
  int off = offsets[e];

  __shared__ __align__(16) unsigned short As[2][8][128][8];  // 32 KB
  __shared__ __align__(16) unsigned short Bs[2][8][64][8];   // 16 KB

  int tid  = threadIdx.x;
  int lane = tid & 63;
  int wave = tid >> 6;
  int wm = wave >> 1;
  int wn = wave & 1;

  const unsigned short* asrc = hbuf + (size_t)((off + m0) >> 7) * (INTERN * 128);

  int brow = tid >> 2;
  int bq   = tid & 3;
  int kgw0 = bq * 2, kgw1 = bq * 2 + 1;
  const float* bsrc = down + (size_t)e * HID * INTERN + (size_t)(n0 + brow) * INTERN + bq * 16;

  f32x4 acc[4][2];
#pragma unroll
  for (int m = 0; m < 4; ++m)
#pragma unroll
    for (int n = 0; n < 2; ++n) acc[m][n] = (f32x4){0.f, 0.f, 0.f, 0.f};

  float4 b0, b1, b2, b3;   // single in-flight B reg set

  // ---- prologue ----
  {
    char* base = (char*)&As[0][0][0][0];
#pragma unroll
    for (int o = 0; o < 4; ++o)
      gload_lds16(asrc + o * 2048 + (size_t)tid * 8, base + o * 4096 + (size_t)tid * 16);
    const float4* bp = (const float4*)bsrc;
    float4 t0 = bp[0], t1 = bp[1], t2 = bp[2], t3 = bp[3];
    *((u16x8*)&Bs[0][kgw0][brow ^ kgw0][0]) = cvt8(t0, t1);
    *((u16x8*)&Bs[0][kgw1][brow ^ kgw1][0]) = cvt8(t2, t3);
    const float4* bp1 = (const float4*)(bsrc + 64);
    b0 = bp1[0]; b1 = bp1[1]; b2 = bp1[2]; b3 = bp1[3];
    WAIT_LGKM0(); SCHED_FENCE();
  }

  int cur = 0;
  const int NT = INTERN / 64;   // 32
  for (int t = 0; t < NT; ++t) {
    WAIT_VM4(); SCHED_FENCE();          // drains the 4-oldest (A quad); B stays in flight
    __builtin_amdgcn_s_barrier(); SCHED_FENCE();
    int nxt = cur ^ 1;
    int ka = (t + 1 < NT) ? (t + 1) * 64 : 0;
    {
      char* base = (char*)&As[nxt][0][0][0];
      const unsigned short* ak = asrc + (size_t)ka * 128;
#pragma unroll
      for (int o = 0; o < 4; ++o)
        gload_lds16(ak + o * 2048 + (size_t)tid * 8, base + o * 4096 + (size_t)tid * 16);
    }
    SCHED_FENCE();
    // compute current tile
#pragma unroll
    for (int kk = 0; kk < 2; ++kk) {
      int kg = kk * 4 + (lane >> 4);
      int rl = lane & 15;
      bf16x8 af[4], bfv[2];
#pragma unroll
      for (int m = 0; m < 4; ++m)
        af[m] = *((const bf16x8*)&As[cur][kg][wm * 64 + m * 16 + rl][0]);
#pragma unroll
      for (int n = 0; n < 2; ++n)
        bfv[n] = *((const bf16x8*)&Bs[cur][kg][(wn * 32 + n * 16 + rl) ^ kg][0]);
#pragma unroll
      for (int m = 0; m < 4; ++m)
#pragma unroll
        for (int n = 0; n < 2; ++n)
          acc[m][n] = __builtin_amdgcn_mfma_f32_16x16x32_bf16(af[m], bfv[n], acc[m][n], 0, 0, 0);
    }
    // stage B(t+1) -> LDS[nxt]
    *((u16x8*)&Bs[nxt][kgw0][brow ^ kgw0][0]) = cvt8(b0, b1);
    *((u16x8*)&Bs[nxt][kgw1][brow ^ kgw1][0]) = cvt8(b2, b3);
    SCHED_FENCE();
    // issue B(t+2)
    {
      int kb = (t + 2 < NT) ? (t + 2) * 64 : 0;
      const float4* bp = (const float4*)(bsrc + kb);
      b0 = bp[0]; b1 = bp[1]; b2 = bp[2]; b3 = bp[3];
    }
    WAIT_LGKM0(); SCHED_FENCE();
    cur = nxt;
  }
  WAIT_VM0();

  int rl = lane & 15;
  int rq = lane >> 4;
#pragma unroll
  for (int m = 0; m < 4; ++m) {
#pragma unroll
    for (int n = 0; n < 2; ++n) {
      int col = n0 + wn * 32 + n * 16 + rl;
#pragma unroll
      for (int j = 0; j < 4; ++j) {
        int lr = wm * 64 + m * 16 + rq * 4 + j;
        if (m0 + lr < Ne)
          ybuf[(size_t)(off + m0 + lr) * HID + col] = f32_to_bf16(acc[m][n][j]);
      }
    }
  }
}

// ---------------- final combine ----------------
__global__ void combine_kernel(const int* __restrict__ pos_map,
                               const float* __restrict__ wgt_map,
                               const unsigned short* __restrict__ ybuf,
                               float* __restrict__ out) {
  int i  = blockIdx.x * 256 + threadIdx.x;
  int t  = i >> 7;
  int c8 = i & 127;
  int p0 = pos_map[2 * t];
  int p1 = pos_map[2 * t + 1];
  float w0 = wgt_map[2 * t];
  float w1 = wgt_map[2 * t + 1];
  float acc[8];
#pragma unroll
  for (int j = 0; j < 8; ++j) acc[j] = 0.f;
  if (p0 >= 0) {
    u16x8 v = *((const u16x8*)(ybuf + (size_t)p0 * HID + c8 * 8));
#pragma unroll
    for (int j = 0; j < 8; ++j) acc[j] += w0 * bf16_to_f32(v[j]);
  }
  if (p1 >= 0) {
    u16x8 v = *((const u16x8*)(ybuf + (size_t)p1 * HID + c8 * 8));
#pragma unroll
    for (int j = 0; j < 8; ++j) acc[j] += w1 * bf16_to_f32(v[j]);
  }
  float4 o0 = make_float4(acc[0], acc[1], acc[2], acc[3]);
  float4 o1 = make_float4(acc[4], acc[5], acc[6], acc[7]);
  float4* dst = (float4*)(out + (size_t)t * HID + c8 * 8);
  dst[0] = o0;
  dst[1] = o1;
}

// ---------------- launch ----------------
extern "C" void kernel_launch(void* const* d_in, const int* in_sizes, int n_in,
                              void* d_out, int out_size, void* d_ws, size_t ws_size,
                              hipStream_t stream) {
  (void)in_sizes; (void)n_in; (void)out_size;
  const float* hidden = (const float*)d_in[0];
  const int*   tki    = (const int*)d_in[1];
  const float* tkw    = (const float*)d_in[2];
  const float* gup    = (const float*)d_in[3];
  const float* down   = (const float*)d_in[4];
  float* out = (float*)d_out;
  char*  ws  = (char*)d_ws;

  int*   counts   = (int*)  (ws + 0);
  int*   offsets  = (int*)  (ws + 64);
  int*   tok_list = (int*)  (ws + 256);
  int*   pos_map  = (int*)  (ws + 65792);
  float* wgt_map  = (float*)(ws + 82176);
  float* w_list   = (float*)(ws + 98560);
  unsigned short* hbuf = (unsigned short*)(ws + 4358400);   // MAXPOS*2048 bf16 (blocked)
  unsigned short* ybuf = (unsigned short*)(ws + 25854208);  // MAXPOS*1024 bf16
  unsigned short* xg   = ybuf;  // alias: xg fully consumed by gemm1 before gemm2 writes ybuf

  if (ws_size < 36602112ull) return;

  hipLaunchKernelGGL(route_kernel, dim3(1), dim3(256), 0, stream,
                     tki, tkw, counts, offsets, tok_list, w_list, pos_map, wgt_map);
  hipLaunchKernelGGL(gather_cvt_x_kernel, dim3(MAXPOS / 2), dim3(256), 0, stream,
                     hidden, counts, offsets, tok_list, xg);
  hipLaunchKernelGGL(gemm1_kernel, dim3(INTERN / 64, T_TOK / 128, NEXP), dim3(256), 0, stream,
                     xg, gup, counts, offsets, hbuf);
  hipLaunchKernelGGL(gemm2_kernel, dim3(HID / 64, T_TOK / 128, NEXP), dim3(256), 0, stream,
                     hbuf, down, counts, offsets, ybuf);
  hipLaunchKernelGGL(combine_kernel, dim3(T_TOK * HID / 8 / 256), dim3(256), 0, stream,
                     pos_map, wgt_map, ybuf, out);
}

// Round 12
// 142.225 us; speedup vs baseline: 1.0014x; 1.0014x over previous
//
#include <hip/hip_runtime.h>
#include <stdint.h>

#define T_TOK  2048
#define HID    1024
#define INTERN 2048
#define NEXP   8
#define MAXPOS 5248   // max 128-aligned routed rows (41 blocks of 128)

typedef __attribute__((ext_vector_type(8))) short          bf16x8;
typedef __attribute__((ext_vector_type(4))) float          f32x4;
typedef __attribute__((ext_vector_type(8))) unsigned short u16x8;
typedef __attribute__((ext_vector_type(4))) unsigned short u16x4;

__device__ __forceinline__ unsigned short f32_to_bf16(float f) {
  unsigned int u = __float_as_uint(f);
  unsigned int r = (u + 0x7FFFu + ((u >> 16) & 1u)) >> 16;
  return (unsigned short)r;
}

__device__ __forceinline__ float bf16_to_f32(unsigned short h) {
  unsigned int u = ((unsigned int)h) << 16;
  return __uint_as_float(u);
}

__device__ __forceinline__ void gload_lds16(const void* g, void* l) {
  __builtin_amdgcn_global_load_lds(
      (const __attribute__((address_space(1))) unsigned int*)g,
      (__attribute__((address_space(3))) unsigned int*)l, 16, 0, 0);
}

// packed f32->bf16 (RTNE) via v_cvt_pk_bf16_f32: 4 inst per 8 elements
__device__ __forceinline__ u16x8 cvt8(float4 a, float4 b) {
  union { u16x8 s; unsigned int u[4]; } r;
  asm("v_cvt_pk_bf16_f32 %0, %1, %2" : "=v"(r.u[0]) : "v"(a.x), "v"(a.y));
  asm("v_cvt_pk_bf16_f32 %0, %1, %2" : "=v"(r.u[1]) : "v"(a.z), "v"(a.w));
  asm("v_cvt_pk_bf16_f32 %0, %1, %2" : "=v"(r.u[2]) : "v"(b.x), "v"(b.y));
  asm("v_cvt_pk_bf16_f32 %0, %1, %2" : "=v"(r.u[3]) : "v"(b.z), "v"(b.w));
  return r.s;
}

#define WAIT_VM0()    asm volatile("s_waitcnt vmcnt(0)" ::: "memory")
#define WAIT_VM4()    asm volatile("s_waitcnt vmcnt(4)" ::: "memory")
#define WAIT_LGKM0()  asm volatile("s_waitcnt lgkmcnt(0)" ::: "memory")
#define SCHED_FENCE() __builtin_amdgcn_sched_barrier(0)

// ---------------- routing ----------------
__global__ void route_kernel(const int* __restrict__ tki,
                             const float* __restrict__ tkw,
                             int* __restrict__ counts,
                             int* __restrict__ offsets,
                             int* __restrict__ tok_list,
                             float* __restrict__ w_list,
                             int* __restrict__ pos_map,
                             float* __restrict__ wgt_map) {
  __shared__ int scnt[NEXP];
  __shared__ int soff[NEXP];
  int tid = threadIdx.x;
  if (tid < NEXP) scnt[tid] = 0;
  __syncthreads();
  for (int t = tid; t < T_TOK; t += 256) {
    int e0 = tki[2 * t] & 7;
    int e1 = tki[2 * t + 1] & 7;
    float w0 = tkw[2 * t];
    float w1 = tkw[2 * t + 1];
    if (e0 == e1) {
      int p = atomicAdd(&scnt[e0], 1);
      tok_list[e0 * T_TOK + p] = t;
      w_list [e0 * T_TOK + p] = w0 + w1;
      pos_map[2 * t]     = (p << 3) | e0;
      wgt_map[2 * t]     = w0 + w1;
      pos_map[2 * t + 1] = -1;
      wgt_map[2 * t + 1] = 0.0f;
    } else {
      int p = atomicAdd(&scnt[e0], 1);
      tok_list[e0 * T_TOK + p] = t;
      w_list [e0 * T_TOK + p] = w0;
      pos_map[2 * t]     = (p << 3) | e0;
      wgt_map[2 * t]     = w0;
      int q = atomicAdd(&scnt[e1], 1);
      tok_list[e1 * T_TOK + q] = t;
      w_list [e1 * T_TOK + q] = w1;
      pos_map[2 * t + 1] = (q << 3) | e1;
      wgt_map[2 * t + 1] = w1;
    }
  }
  __syncthreads();
  if (tid == 0) {
    int acc = 0;
    for (int e = 0; e < NEXP; ++e) {
      counts[e]  = scnt[e];
      offsets[e] = acc;
      soff[e]    = acc;
      acc += ((scnt[e] + 127) >> 7) << 7;
    }
  }
  __syncthreads();
  for (int i = tid; i < 2 * T_TOK; i += 256) {
    int v = pos_map[i];
    if (v >= 0) pos_map[i] = soff[v & 7] + (v >> 3);
  }
}

// ---------------- fused gather + f32->bf16: hidden -> blocked xg ----------------
__global__ void gather_cvt_x_kernel(const float* __restrict__ hidden,
                                    const int* __restrict__ counts,
                                    const int* __restrict__ offsets,
                                    const int* __restrict__ tok_list,
                                    unsigned short* __restrict__ xg) {
  int p = blockIdx.x * 2 + (threadIdx.x >> 7);   // routed position
  int c = threadIdx.x & 127;                     // 8-elem column group
  int e = 0;
#pragma unroll
  for (int k = 1; k < NEXP; ++k) if (p >= offsets[k]) e = k;
  int r = p - offsets[e];
  float4 a = {0.f, 0.f, 0.f, 0.f}, b = {0.f, 0.f, 0.f, 0.f};
  if (r < counts[e]) {
    int tok = tok_list[e * T_TOK + r];
    const float4* src = (const float4*)(hidden + (size_t)tok * HID + c * 8);
    a = src[0]; b = src[1];
  }
  *((u16x8*)(xg + (size_t)(p >> 7) * 131072 + c * 1024 + (p & 127) * 8)) = cvt8(a, b);
}

// ---------------- GEMM1: h = gelu_tanh(X Wg^T) * (X Wu^T) ----------------
// BK=64 (gemm2-cloned phase length), A-frags direct from blocked xg in registers
// (single set, reloaded after last use), B: 8 float4 in flight + cvt_pk + swizzled
// LDS double-buffer (32 KB total). One barrier per 64-K iteration.
__global__ __launch_bounds__(256, 3)
void gemm1_kernel(const unsigned short* __restrict__ xg,
                  const float* __restrict__ gup,
                  const int* __restrict__ counts,
                  const int* __restrict__ offsets,
                  unsigned short* __restrict__ hbuf) {
  int e  = blockIdx.z;
  int Ne = counts[e];
  int m0 = blockIdx.y * 128;
  if (m0 >= Ne) return;
  int n0  = blockIdx.x * 64;
  int off = offsets[e];

  __shared__ __align__(16) unsigned short Gs[2][8][64][8];   // 16 KB
  __shared__ __align__(16) unsigned short Us[2][8][64][8];   // 16 KB

  int tid  = threadIdx.x;
  int lane = tid & 63;
  int wave = tid >> 6;
  int wm = wave >> 1;
  int wn = wave & 1;
  int kg4 = lane >> 4;     // 0..3
  int rl  = lane & 15;

  // A direct-load base: blocked xg chunk for rows [m0, m0+128)
  const unsigned short* afbase = xg + (size_t)((off + m0) >> 7) * (HID * 128)
                               + rl * 8 + wm * 512;

  // B staging (gemm2 pattern): brow 0..63, bq covers 16 k-values
  int brow = tid >> 2;
  int bq   = tid & 3;
  int kgw0 = bq * 2, kgw1 = bq * 2 + 1;
  int brw0 = brow ^ kgw0, brw1 = brow ^ kgw1;
  const float* gsrc = gup + (size_t)e * (2 * INTERN) * HID + (size_t)(n0 + brow) * HID + bq * 16;
  const float* usrc = gsrc + (size_t)INTERN * HID;

  f32x4 accg[4][2], accu[4][2];
#pragma unroll
  for (int m = 0; m < 4; ++m)
#pragma unroll
    for (int n = 0; n < 2; ++n) {
      accg[m][n] = (f32x4){0.f, 0.f, 0.f, 0.f};
      accu[m][n] = (f32x4){0.f, 0.f, 0.f, 0.f};
    }

  const int NT = HID / 64;   // 16

  // A fragment set: kk-half 0 (a00..a03) and 1 (a10..a13), m = 0..3
  bf16x8 a00, a01, a02, a03, a10, a11, a12, a13;
  // B f32 in-flight regs (hold tile t+1)
  float4 g0, g1, g2, g3, u0, u1, u2, u3;

  // ---- prologue: B(0)->LDS0; A(0)->regs; B(1)->regs ----
  {
    const float4* gp = (const float4*)gsrc;
    const float4* up = (const float4*)usrc;
    float4 tg0 = gp[0], tg1 = gp[1], tg2 = gp[2], tg3 = gp[3];
    float4 tu0 = up[0], tu1 = up[1], tu2 = up[2], tu3 = up[3];
    *((u16x8*)&Gs[0][kgw0][brw0][0]) = cvt8(tg0, tg1);
    *((u16x8*)&Gs[0][kgw1][brw1][0]) = cvt8(tg2, tg3);
    *((u16x8*)&Us[0][kgw0][brw0][0]) = cvt8(tu0, tu1);
    *((u16x8*)&Us[0][kgw1][brw1][0]) = cvt8(tu2, tu3);
    const unsigned short* ap0 = afbase + (size_t)(0 * 8 + kg4) * 1024;
    const unsigned short* ap1 = afbase + (size_t)(0 * 8 + 4 + kg4) * 1024;
    a00 = *((const bf16x8*)(ap0));       a01 = *((const bf16x8*)(ap0 + 128));
    a02 = *((const bf16x8*)(ap0 + 256)); a03 = *((const bf16x8*)(ap0 + 384));
    a10 = *((const bf16x8*)(ap1));       a11 = *((const bf16x8*)(ap1 + 128));
    a12 = *((const bf16x8*)(ap1 + 256)); a13 = *((const bf16x8*)(ap1 + 384));
    const float4* gp1 = (const float4*)(gsrc + 64);
    const float4* up1 = (const float4*)(usrc + 64);
    g0 = gp1[0]; g1 = gp1[1]; g2 = gp1[2]; g3 = gp1[3];
    u0 = up1[0]; u1 = up1[1]; u2 = up1[2]; u3 = up1[3];
    WAIT_LGKM0(); SCHED_FENCE();
    __builtin_amdgcn_s_barrier(); SCHED_FENCE();
  }

  int cur = 0;
  for (int t = 0; t < NT; ++t) {
    int nxt = cur ^ 1;
    // ---- MFMA phase: kk=0 then kk=1 (32 MFMA total) ----
    {
      bf16x8 gf[2], uf[2];
      int kg8 = kg4;               // kk = 0
#pragma unroll
      for (int n = 0; n < 2; ++n) {
        int r_ = (wn * 32 + n * 16 + rl) ^ kg8;
        gf[n] = *((const bf16x8*)&Gs[cur][kg8][r_][0]);
        uf[n] = *((const bf16x8*)&Us[cur][kg8][r_][0]);
      }
#pragma unroll
      for (int n = 0; n < 2; ++n) {
        accg[0][n] = __builtin_amdgcn_mfma_f32_16x16x32_bf16(a00, gf[n], accg[0][n], 0, 0, 0);
        accu[0][n] = __builtin_amdgcn_mfma_f32_16x16x32_bf16(a00, uf[n], accu[0][n], 0, 0, 0);
        accg[1][n] = __builtin_amdgcn_mfma_f32_16x16x32_bf16(a01, gf[n], accg[1][n], 0, 0, 0);
        accu[1][n] = __builtin_amdgcn_mfma_f32_16x16x32_bf16(a01, uf[n], accu[1][n], 0, 0, 0);
        accg[2][n] = __builtin_amdgcn_mfma_f32_16x16x32_bf16(a02, gf[n], accg[2][n], 0, 0, 0);
        accu[2][n] = __builtin_amdgcn_mfma_f32_16x16x32_bf16(a02, uf[n], accu[2][n], 0, 0, 0);
        accg[3][n] = __builtin_amdgcn_mfma_f32_16x16x32_bf16(a03, gf[n], accg[3][n], 0, 0, 0);
        accu[3][n] = __builtin_amdgcn_mfma_f32_16x16x32_bf16(a03, uf[n], accu[3][n], 0, 0, 0);
      }
      kg8 = 4 + kg4;               // kk = 1
#pragma unroll
      for (int n = 0; n < 2; ++n) {
        int r_ = (wn * 32 + n * 16 + rl) ^ kg8;
        gf[n] = *((const bf16x8*)&Gs[cur][kg8][r_][0]);
        uf[n] = *((const bf16x8*)&Us[cur][kg8][r_][0]);
      }
#pragma unroll
      for (int n = 0; n < 2; ++n) {
        accg[0][n] = __builtin_amdgcn_mfma_f32_16x16x32_bf16(a10, gf[n], accg[0][n], 0, 0, 0);
        accu[0][n] = __builtin_amdgcn_mfma_f32_16x16x32_bf16(a10, uf[n], accu[0][n], 0, 0, 0);
        accg[1][n] = __builtin_amdgcn_mfma_f32_16x16x32_bf16(a11, gf[n], accg[1][n], 0, 0, 0);
        accu[1][n] = __builtin_amdgcn_mfma_f32_16x16x32_bf16(a11, uf[n], accu[1][n], 0, 0, 0);
        accg[2][n] = __builtin_amdgcn_mfma_f32_16x16x32_bf16(a12, gf[n], accg[2][n], 0, 0, 0);
        accu[2][n] = __builtin_amdgcn_mfma_f32_16x16x32_bf16(a12, uf[n], accu[2][n], 0, 0, 0);
        accg[3][n] = __builtin_amdgcn_mfma_f32_16x16x32_bf16(a13, gf[n], accg[3][n], 0, 0, 0);
        accu[3][n] = __builtin_amdgcn_mfma_f32_16x16x32_bf16(a13, uf[n], accu[3][n], 0, 0, 0);
      }
    }
    SCHED_FENCE();
    // ---- reload A regs with tile t+1 (after last use; ~1 iter of cover, L2-hot) ----
    {
      int tn = (t + 1 < NT) ? t + 1 : 0;
      const unsigned short* ap0 = afbase + (size_t)(tn * 8 + kg4) * 1024;
      const unsigned short* ap1 = afbase + (size_t)(tn * 8 + 4 + kg4) * 1024;
      a00 = *((const bf16x8*)(ap0));       a01 = *((const bf16x8*)(ap0 + 128));
      a02 = *((const bf16x8*)(ap0 + 256)); a03 = *((const bf16x8*)(ap0 + 384));
      a10 = *((const bf16x8*)(ap1));       a11 = *((const bf16x8*)(ap1 + 128));
      a12 = *((const bf16x8*)(ap1 + 256)); a13 = *((const bf16x8*)(ap1 + 384));
    }
    SCHED_FENCE();
    // ---- stage B(t+1) regs -> LDS[nxt] ----
    *((u16x8*)&Gs[nxt][kgw0][brw0][0]) = cvt8(g0, g1);
    *((u16x8*)&Gs[nxt][kgw1][brw1][0]) = cvt8(g2, g3);
    *((u16x8*)&Us[nxt][kgw0][brw0][0]) = cvt8(u0, u1);
    *((u16x8*)&Us[nxt][kgw1][brw1][0]) = cvt8(u2, u3);
    SCHED_FENCE();
    // ---- issue B(t+2) ----
    {
      int kb = (t + 2 < NT) ? (t + 2) * 64 : 0;
      const float4* gp = (const float4*)(gsrc + kb);
      const float4* up = (const float4*)(usrc + kb);
      g0 = gp[0]; g1 = gp[1]; g2 = gp[2]; g3 = gp[3];
      u0 = up[0]; u1 = up[1]; u2 = up[2]; u3 = up[3];
    }
    WAIT_LGKM0(); SCHED_FENCE();
    __builtin_amdgcn_s_barrier(); SCHED_FENCE();
    cur = nxt;
  }

  int rq = lane >> 4;
  size_t hb_base = (size_t)((off + m0) >> 7) * (INTERN * 128);
#pragma unroll
  for (int m = 0; m < 4; ++m) {
#pragma unroll
    for (int n = 0; n < 2; ++n) {
      int col = n0 + wn * 32 + n * 16 + rl;
      size_t cbase = hb_base + (size_t)(col >> 3) * 1024 + (col & 7);
#pragma unroll
      for (int j = 0; j < 4; ++j) {
        int lr = wm * 64 + m * 16 + rq * 4 + j;
        if (m0 + lr < Ne) {
          float gv = accg[m][n][j];
          float uv = accu[m][n][j];
          float tt2 = gv + 0.044715f * gv * gv * gv;
          float a  = gv / (1.0f + __expf(-1.5957691216f * tt2));  // == gelu_pytorch_tanh
          hbuf[cbase + (size_t)lr * 8] = f32_to_bf16(a * uv);
        }
      }
    }
  }
}

// ---------------- GEMM2: y = h Wd^T (blocked-A, BK=64, late-B + vmcnt(4)) ----------------
__global__ __launch_bounds__(256, 2)
void gemm2_kernel(const unsigned short* __restrict__ hbuf,
                  const float* __restrict__ down,
                  const int* __restrict__ counts,
                  const int* __restrict__ offsets,
                  unsigned short* __restrict__ ybuf) {
  int e  = blockIdx.z;
  int Ne = counts[e];
  int m0 = blockIdx.y * 128;
  if (m0 >= Ne) return;
  int n0  = blockIdx.x * 64;
  int off = offsets[e];

  __shared__ __align__(16) unsigned short As[2][8][128][8];  // 32 KB
  __shared__ __align__(16) unsigned short Bs[2][8][64][8];   // 16 KB

  int tid  = threadIdx.x;
  int lane = tid & 63;
  int wave = tid >> 6;
  int wm = wave >> 1;
  int wn = wave & 1;

  const unsigned short* asrc = hbuf + (size_t)((off + m0) >> 7) * (INTERN * 128);

  int brow = tid >> 2;
  int bq   = tid & 3;
  int kgw0 = bq * 2, kgw1 = bq * 2 + 1;
  const float* bsrc = down + (size_t)e * HID * INTERN + (size_t)(n0 + brow) * INTERN + bq * 16;

  f32x4 acc[4][2];
#pragma unroll
  for (int m = 0; m < 4; ++m)
#pragma unroll
    for (int n = 0; n < 2; ++n) acc[m][n] = (f32x4){0.f, 0.f, 0.f, 0.f};

  float4 b0, b1, b2, b3;   // single in-flight B reg set

  // ---- prologue ----
  {
    char* base = (char*)&As[0][0][0][0];
#pragma unroll
    for (int o = 0; o < 4; ++o)
      gload_lds16(asrc + o * 2048 + (size_t)tid * 8, base + o * 4096 + (size_t)tid * 16);
    const float4* bp = (const float4*)bsrc;
    float4 t0 = bp[0], t1 = bp[1], t2 = bp[2], t3 = bp[3];
    *((u16x8*)&Bs[0][kgw0][brow ^ kgw0][0]) = cvt8(t0, t1);
    *((u16x8*)&Bs[0][kgw1][brow ^ kgw1][0]) = cvt8(t2, t3);
    const float4* bp1 = (const float4*)(bsrc + 64);
    b0 = bp1[0]; b1 = bp1[1]; b2 = bp1[2]; b3 = bp1[3];
    WAIT_LGKM0(); SCHED_FENCE();
  }

  int cur = 0;
  const int NT = INTERN / 64;   // 32
  for (int t = 0; t < NT; ++t) {
    WAIT_VM4(); SCHED_FENCE();          // drains the 4-oldest (A quad); B stays in flight
    __builtin_amdgcn_s_barrier(); SCHED_FENCE();
    int nxt = cur ^ 1;
    int ka = (t + 1 < NT) ? (t + 1) * 64 : 0;
    {
      char* base = (char*)&As[nxt][0][0][0];
      const unsigned short* ak = asrc + (size_t)ka * 128;
#pragma unroll
      for (int o = 0; o < 4; ++o)
        gload_lds16(ak + o * 2048 + (size_t)tid * 8, base + o * 4096 + (size_t)tid * 16);
    }
    SCHED_FENCE();
    // compute current tile
#pragma unroll
    for (int kk = 0; kk < 2; ++kk) {
      int kg = kk * 4 + (lane >> 4);
      int rl = lane & 15;
      bf16x8 af[4], bfv[2];
#pragma unroll
      for (int m = 0; m < 4; ++m)
        af[m] = *((const bf16x8*)&As[cur][kg][wm * 64 + m * 16 + rl][0]);
#pragma unroll
      for (int n = 0; n < 2; ++n)
        bfv[n] = *((const bf16x8*)&Bs[cur][kg][(wn * 32 + n * 16 + rl) ^ kg][0]);
#pragma unroll
      for (int m = 0; m < 4; ++m)
#pragma unroll
        for (int n = 0; n < 2; ++n)
          acc[m][n] = __builtin_amdgcn_mfma_f32_16x16x32_bf16(af[m], bfv[n], acc[m][n], 0, 0, 0);
    }
    // stage B(t+1) -> LDS[nxt]
    *((u16x8*)&Bs[nxt][kgw0][brow ^ kgw0][0]) = cvt8(b0, b1);
    *((u16x8*)&Bs[nxt][kgw1][brow ^ kgw1][0]) = cvt8(b2, b3);
    SCHED_FENCE();
    // issue B(t+2)
    {
      int kb = (t + 2 < NT) ? (t + 2) * 64 : 0;
      const float4* bp = (const float4*)(bsrc + kb);
      b0 = bp[0]; b1 = bp[1]; b2 = bp[2]; b3 = bp[3];
    }
    WAIT_LGKM0(); SCHED_FENCE();
    cur = nxt;
  }
  WAIT_VM0();

  int rl = lane & 15;
  int rq = lane >> 4;
#pragma unroll
  for (int m = 0; m < 4; ++m) {
#pragma unroll
    for (int n = 0; n < 2; ++n) {
      int col = n0 + wn * 32 + n * 16 + rl;
#pragma unroll
      for (int j = 0; j < 4; ++j) {
        int lr = wm * 64 + m * 16 + rq * 4 + j;
        if (m0 + lr < Ne)
          ybuf[(size_t)(off + m0 + lr) * HID + col] = f32_to_bf16(acc[m][n][j]);
      }
    }
  }
}

// ---------------- final combine ----------------
__global__ void combine_kernel(const int* __restrict__ pos_map,
                               const float* __restrict__ wgt_map,
                               const unsigned short* __restrict__ ybuf,
                               float* __restrict__ out) {
  int i  = blockIdx.x * 256 + threadIdx.x;
  int t  = i >> 7;
  int c8 = i & 127;
  int p0 = pos_map[2 * t];
  int p1 = pos_map[2 * t + 1];
  float w0 = wgt_map[2 * t];
  float w1 = wgt_map[2 * t + 1];
  float acc[8];
#pragma unroll
  for (int j = 0; j < 8; ++j) acc[j] = 0.f;
  if (p0 >= 0) {
    u16x8 v = *((const u16x8*)(ybuf + (size_t)p0 * HID + c8 * 8));
#pragma unroll
    for (int j = 0; j < 8; ++j) acc[j] += w0 * bf16_to_f32(v[j]);
  }
  if (p1 >= 0) {
    u16x8 v = *((const u16x8*)(ybuf + (size_t)p1 * HID + c8 * 8));
#pragma unroll
    for (int j = 0; j < 8; ++j) acc[j] += w1 * bf16_to_f32(v[j]);
  }
  float4 o0 = make_float4(acc[0], acc[1], acc[2], acc[3]);
  float4 o1 = make_float4(acc[4], acc[5], acc[6], acc[7]);
  float4* dst = (float4*)(out + (size_t)t * HID + c8 * 8);
  dst[0] = o0;
  dst[1] = o1;
}

// ---------------- launch ----------------
extern "C" void kernel_launch(void* const* d_in, const int* in_sizes, int n_in,
                              void* d_out, int out_size, void* d_ws, size_t ws_size,
                              hipStream_t stream) {
  (void)in_sizes; (void)n_in; (void)out_size;
  const float* hidden = (const float*)d_in[0];
  const int*   tki    = (const int*)d_in[1];
  const float* tkw    = (const float*)d_in[2];
  const float* gup    = (const float*)d_in[3];
  const float* down   = (const float*)d_in[4];
  float* out = (float*)d_out;
  char*  ws  = (char*)d_ws;

  int*   counts   = (int*)  (ws + 0);
  int*   offsets  = (int*)  (ws + 64);
  int*   tok_list = (int*)  (ws + 256);
  int*   pos_map  = (int*)  (ws + 65792);
  float* wgt_map  = (float*)(ws + 82176);
  float* w_list   = (float*)(ws + 98560);
  unsigned short* hbuf = (unsigned short*)(ws + 4358400);   // MAXPOS*2048 bf16 (blocked)
  unsigned short* ybuf = (unsigned short*)(ws + 25854208);  // MAXPOS*1024 bf16
  unsigned short* xg   = ybuf;  // alias: xg fully consumed by gemm1 before gemm2 writes ybuf

  if (ws_size < 36602112ull) return;

  hipLaunchKernelGGL(route_kernel, dim3(1), dim3(256), 0, stream,
                     tki, tkw, counts, offsets, tok_list, w_list, pos_map, wgt_map);
  hipLaunchKernelGGL(gather_cvt_x_kernel, dim3(MAXPOS / 2), dim3(256), 0, stream,
                     hidden, counts, offsets, tok_list, xg);
  hipLaunchKernelGGL(gemm1_kernel, dim3(INTERN / 64, T_TOK / 128, NEXP), dim3(256), 0, stream,
                     xg, gup, counts, offsets, hbuf);
  hipLaunchKernelGGL(gemm2_kernel, dim3(HID / 64, T_TOK / 128, NEXP), dim3(256), 0, stream,
                     hbuf, down, counts, offsets, ybuf);
  hipLaunchKernelGGL(combine_kernel, dim3(T_TOK * HID / 8 / 256), dim3(256), 0, stream,
                     pos_map, wgt_map, ybuf, out);
}